// Round 5
// baseline (128.290 us; speedup 1.0000x reference)
//
#include <hip/hip_runtime.h>
#include <cfloat>

// VectorQuantizer: inputs [65536,64] f32, embeddings [2048,64] f32
#define N_TOTAL 65536
#define DIM     64
#define NEMB    2048

typedef __attribute__((ext_vector_type(8))) _Float16 half8;   // MFMA A/B frag (4 VGPRs)
typedef __attribute__((ext_vector_type(4))) float    floatx4; // MFMA C/D frag

// ---------------------------------------------------------------------------
// Prep: pack embeddings as f16 in MFMA-B frag-major layout
//   chunk c = (g*2 + ks)*64 + lane, lane = q*16 + n:
//   ehp[c] = e_f16[col = g*16+n][k = ks*32 + q*8 .. +8)
// One 32-col tile = 4 KB contiguous -> 4 flat global_load_lds issues.
// Also fp32 norms -> en[2048].
// ---------------------------------------------------------------------------
__global__ void prep_kernel(const float* __restrict__ emb,
                            half8* __restrict__ ehp, float* __restrict__ en) {
    const int t = blockIdx.x * 256 + threadIdx.x;   // 16384 threads
    {
        const int l   = t & 63;
        const int ks  = (t >> 6) & 1;
        const int g   = t >> 7;
        const int col = g * 16 + (l & 15);
        const int kb  = ks * 32 + (l >> 4) * 8;
        const float* s = emb + col * DIM + kb;
        float4 v0 = *(const float4*)s, v1 = *(const float4*)(s + 4);
        half8 hv;
        hv[0] = (_Float16)v0.x; hv[1] = (_Float16)v0.y;
        hv[2] = (_Float16)v0.z; hv[3] = (_Float16)v0.w;
        hv[4] = (_Float16)v1.x; hv[5] = (_Float16)v1.y;
        hv[6] = (_Float16)v1.z; hv[7] = (_Float16)v1.w;
        ehp[t] = hv;
    }
    if (t < NEMB * 4) {
        const int row = t >> 2, seg = t & 3;
        const float* s = emb + row * DIM + seg * 16;
        float acc = 0.f;
#pragma unroll
        for (int i = 0; i < 4; ++i) {
            float4 v = ((const float4*)s)[i];
            acc = fmaf(v.x, v.x, acc); acc = fmaf(v.y, v.y, acc);
            acc = fmaf(v.z, v.z, acc); acc = fmaf(v.w, v.w, acc);
        }
        acc += __shfl_xor(acc, 1, 64);
        acc += __shfl_xor(acc, 2, 64);
        if (seg == 0) en[row] = acc;
    }
}

// ---------------------------------------------------------------------------
// Main. Block = 4 waves, 64 rows. Wave pair p shares 32 rows; half h scans
// cols [h*1024, +1024) in 32 tiles of 32 cols. Per-wave DOUBLE-BUFFERED
// global_load_lds staging with fine-grained vmcnt(4): issue tile t+1's 4
// DMAs, wait only tile t, compute. Zero barriers in the K-loop. Norms live
// in LDS (staged once). B-frags read via one asm block (4x ds_read_b128 +
// lgkmcnt(0)) so the compiler can't insert a conservative vmcnt(0).
//   approx q = x.eh - ||e||^2/2 + 128 (f16 2-limb x, 1-limb e)
//   packed key = (bits(q) & ~63) | (63-L); branchless top-2 min/max/max.
//   Epilogue: exact fp32 rescore of 4 candidates (top-2 per half).
// ---------------------------------------------------------------------------
__global__ __launch_bounds__(256, 3) void vq_mfma_kernel(
        const float* __restrict__ x, const float* __restrict__ emb,
        const char* __restrict__ ehb, const float* __restrict__ eng,
        float* __restrict__ quant, float* __restrict__ idxf,
        float* __restrict__ flat) {

    __shared__ uint4 Stage[4][2][256];   // 32 KB: per-wave ping-pong (4 KB each)
    __shared__ float EnS[NEMB];          // 8 KB: all norms
    __shared__ uint4 Mrg[2][64];         // 2 KB: per-half top-2 candidates

    const int t    = threadIdx.x;
    const int wave = t >> 6, lane = t & 63;
    const int n = lane & 15, q = lane >> 4;
    const int h = wave & 1, p = wave >> 1;
    const int blk0 = blockIdx.x * 64;
    const int row0 = blk0 + p * 32;

    // ---- flat_inputs copy (block-coalesced) ----
    {
        const float4* s4 = (const float4*)(x + (size_t)blk0 * DIM);
        float4*       d4 = (float4*)(flat + (size_t)blk0 * DIM);
#pragma unroll
        for (int i = 0; i < 4; ++i) d4[i * 256 + t] = s4[i * 256 + t];
    }
    // ---- stage all norms to LDS ----
    {
        const float4* s4 = (const float4*)eng;
        float4*       d4 = (float4*)EnS;
#pragma unroll
        for (int i = 0; i < 2; ++i) d4[i * 256 + t] = s4[i * 256 + t];
    }

    // ---- A fragments, f16 2-limb split. A[m=lane&15][k=q*8+j] ----
    half8 ah[2][2], al[2][2];
#pragma unroll
    for (int tl = 0; tl < 2; ++tl)
#pragma unroll
        for (int ks = 0; ks < 2; ++ks) {
            const float* pp = x + (size_t)(row0 + tl * 16 + n) * DIM + ks * 32 + q * 8;
            float4 v0 = *(const float4*)pp, v1 = *(const float4*)(pp + 4);
            float xv[8] = {v0.x, v0.y, v0.z, v0.w, v1.x, v1.y, v1.z, v1.w};
#pragma unroll
            for (int j = 0; j < 8; ++j) {
                _Float16 hh = (_Float16)xv[j];
                ah[tl][ks][j] = hh;
                al[tl][ks][j] = (_Float16)(xv[j] - (float)hh);
            }
        }

    __syncthreads();   // EnS visible; drains all vm/lgkm -> clean vmcnt stream

    unsigned best[8], sec[8];
#pragma unroll
    for (int r = 0; r < 8; ++r) { best[r] = 0u; sec[r] = 0u; }

    const char* ebase = ehb + (size_t)h * 131072 + (size_t)lane * 16;

    // ---- prologue: tile 0 DMA into buffer 0 ----
#pragma unroll
    for (int i = 0; i < 4; ++i)
        __builtin_amdgcn_global_load_lds(
            (const __attribute__((address_space(1))) unsigned*)(ebase + i * 1024),
            (__attribute__((address_space(3))) unsigned*)&Stage[wave][0][i * 64],
            16, 0, 0);

#pragma unroll 2
    for (int tile = 0; tile < 32; ++tile) {
        const int buf = tile & 1;
        if (tile < 31) {
            // prev tile's ds_reads already consumed -> lgkmcnt(0) is free; guards WAW
            asm volatile("s_waitcnt lgkmcnt(0)" ::: "memory");
            const char* src = ebase + (size_t)(tile + 1) * 4096;
#pragma unroll
            for (int i = 0; i < 4; ++i)
                __builtin_amdgcn_global_load_lds(
                    (const __attribute__((address_space(1))) unsigned*)(src + i * 1024),
                    (__attribute__((address_space(3))) unsigned*)&Stage[wave][buf ^ 1][i * 64],
                    16, 0, 0);
            asm volatile("s_waitcnt vmcnt(4)" ::: "memory");  // tile done; t+1 in flight
        } else {
            asm volatile("s_waitcnt vmcnt(0)" ::: "memory");  // last tile
        }

        // ---- B frags: 4x ds_read_b128 + lgkmcnt(0), opaque to the waitcnt pass ----
        half8 b00, b01, b10, b11;
        {
            const __attribute__((address_space(3))) char* sb =
                (const __attribute__((address_space(3))) char*)&Stage[wave][buf][0];
            asm volatile("ds_read_b128 %0, %4\n\t"
                         "ds_read_b128 %1, %4 offset:1024\n\t"
                         "ds_read_b128 %2, %4 offset:2048\n\t"
                         "ds_read_b128 %3, %4 offset:3072\n\t"
                         "s_waitcnt lgkmcnt(0)"
                         : "=&v"(b00), "=&v"(b01), "=&v"(b10), "=&v"(b11)
                         : "v"(sb + lane * 16));
        }

#pragma unroll
        for (int sub = 0; sub < 2; ++sub) {
            const int L = tile * 2 + sub;
            const float env = EnS[h * 1024 + L * 16 + n];
            const float enh = fmaf(-0.5f, env, 128.0f);
            floatx4 a0 = {enh, enh, enh, enh};
            floatx4 a1 = a0;
            half8 bk0 = sub ? b10 : b00;
            half8 bk1 = sub ? b11 : b01;
            a0 = __builtin_amdgcn_mfma_f32_16x16x32_f16(ah[0][0], bk0, a0, 0, 0, 0);
            a0 = __builtin_amdgcn_mfma_f32_16x16x32_f16(al[0][0], bk0, a0, 0, 0, 0);
            a1 = __builtin_amdgcn_mfma_f32_16x16x32_f16(ah[1][0], bk0, a1, 0, 0, 0);
            a1 = __builtin_amdgcn_mfma_f32_16x16x32_f16(al[1][0], bk0, a1, 0, 0, 0);
            a0 = __builtin_amdgcn_mfma_f32_16x16x32_f16(ah[0][1], bk1, a0, 0, 0, 0);
            a0 = __builtin_amdgcn_mfma_f32_16x16x32_f16(al[0][1], bk1, a0, 0, 0, 0);
            a1 = __builtin_amdgcn_mfma_f32_16x16x32_f16(ah[1][1], bk1, a1, 0, 0, 0);
            a1 = __builtin_amdgcn_mfma_f32_16x16x32_f16(al[1][1], bk1, a1, 0, 0, 0);

            const unsigned Lp = (unsigned)(63 - L);
#pragma unroll
            for (int r = 0; r < 8; ++r) {
                float v = (r < 4) ? a0[r] : a1[r - 4];
                unsigned key = (__float_as_uint(v) & 0xFFFFFFC0u) | Lp;  // v_and_or_b32
                unsigned lo  = best[r] < key ? best[r] : key;
                best[r] = best[r] > key ? best[r] : key;
                sec[r]  = sec[r] > lo ? sec[r] : lo;
            }
        }
    }

    // ---- decode per-lane top-2 to (bucketed bits, full col) ----
    unsigned bval[8], bcol[8], sval[8], scol[8];
#pragma unroll
    for (int r = 0; r < 8; ++r) {
        bval[r] = best[r] & 0xFFFFFFC0u;
        bcol[r] = (unsigned)(h * 1024 + (63 - (int)(best[r] & 63u)) * 16 + n);
        sval[r] = sec[r] & 0xFFFFFFC0u;
        scol[r] = (unsigned)(h * 1024 + (63 - (int)(sec[r] & 63u)) * 16 + n);
    }
    // ---- butterfly top-2 merge across the 16 n-lanes of each q-group ----
#pragma unroll
    for (int m = 1; m < 16; m <<= 1) {
#pragma unroll
        for (int r = 0; r < 8; ++r) {
            unsigned ov  = (unsigned)__shfl_xor((int)bval[r], m, 64);
            unsigned oc  = (unsigned)__shfl_xor((int)bcol[r], m, 64);
            unsigned ov2 = (unsigned)__shfl_xor((int)sval[r], m, 64);
            unsigned oc2 = (unsigned)__shfl_xor((int)scol[r], m, 64);
            bool ow = (ov > bval[r]) || (ov == bval[r] && oc < bcol[r]);
            unsigned nbv = ow ? ov : bval[r], nbc = ow ? oc : bcol[r];
            unsigned lv  = ow ? bval[r] : ov, lc  = ow ? bcol[r] : oc;
            bool sv2 = (ov2 > sval[r]) || (ov2 == sval[r] && oc2 < scol[r]);
            unsigned bsv = sv2 ? ov2 : sval[r], bsc = sv2 ? oc2 : scol[r];
            bool s3 = (lv > bsv) || (lv == bsv && lc < bsc);
            sval[r] = s3 ? lv : bsv; scol[r] = s3 ? lc : bsc;
            bval[r] = nbv; bcol[r] = nbc;
        }
    }
    // ---- publish per-half candidates (rows: tl*16 + q*4 + r) ----
    if (n == 0) {
#pragma unroll
        for (int r = 0; r < 8; ++r) {
            const int lr = p * 32 + (r >> 2) * 16 + q * 4 + (r & 3);
            Mrg[h][lr] = make_uint4(bval[r], bcol[r], sval[r], scol[r]);
        }
    }
    __syncthreads();

    // ---- exact fp32 rescore of 4 candidates; wave w handles 16 rows ----
#pragma unroll
    for (int r = 0; r < 4; ++r) {
        const int lr   = wave * 16 + q * 4 + r;
        const int grow = blk0 + lr;
        uint4 c0v = Mrg[0][lr], c1v = Mrg[1][lr];
        int cand[4] = {(int)c0v.y, (int)c0v.w, (int)c1v.y, (int)c1v.w};
        float4 xv = *(const float4*)(x + (size_t)grow * DIM + n * 4);
        float pbest = -FLT_MAX; int cbest = 0;
        float4 ebest = {0.f, 0.f, 0.f, 0.f};
#pragma unroll
        for (int c = 0; c < 4; ++c) {
            float4 e = *(const float4*)(emb + (size_t)cand[c] * DIM + n * 4);
            float pp = (xv.x - 0.5f * e.x) * e.x + (xv.y - 0.5f * e.y) * e.y
                     + (xv.z - 0.5f * e.z) * e.z + (xv.w - 0.5f * e.w) * e.w;
#pragma unroll
            for (int m2 = 1; m2 < 16; m2 <<= 1) pp += __shfl_xor(pp, m2, 64);
            bool take = (pp > pbest) || (pp == pbest && cand[c] < cbest);
            pbest = take ? pp : pbest;
            cbest = take ? cand[c] : cbest;
            ebest.x = take ? e.x : ebest.x; ebest.y = take ? e.y : ebest.y;
            ebest.z = take ? e.z : ebest.z; ebest.w = take ? e.w : ebest.w;
        }
        *(float4*)(quant + (size_t)grow * DIM + n * 4) = ebest;
        if (n == 0) idxf[grow] = (float)cbest;
    }
}

extern "C" void kernel_launch(void* const* d_in, const int* in_sizes, int n_in,
                              void* d_out, int out_size, void* d_ws, size_t ws_size,
                              hipStream_t stream) {
    const float* x   = (const float*)d_in[0];   // [65536, 64]
    const float* emb = (const float*)d_in[1];   // [2048, 64]
    float* out   = (float*)d_out;
    float* quant = out;                               // 4194304 floats
    float* idxf  = out + (size_t)N_TOTAL * DIM;       // 65536 floats
    float* flat  = idxf + N_TOTAL;                    // 4194304 floats

    half8* ehp = (half8*)d_ws;                        // 2048*64 f16 frag-major (256 KB)
    float* en  = (float*)((char*)d_ws + (size_t)NEMB * DIM * 2);  // 2048 f32

    prep_kernel<<<64, 256, 0, stream>>>(emb, ehp, en);
    vq_mfma_kernel<<<N_TOTAL / 64, 256, 0, stream>>>(x, emb, (const char*)ehp, en,
                                                     quant, idxf, flat);
}

// Round 6
// 121.772 us; speedup vs baseline: 1.0535x; 1.0535x over previous
//
#include <hip/hip_runtime.h>
#include <cfloat>

// VectorQuantizer: inputs [65536,64] f32, embeddings [2048,64] f32
#define N_TOTAL 65536
#define DIM     64
#define NEMB    2048

typedef __attribute__((ext_vector_type(8))) _Float16 half8;   // MFMA A/B frag (4 VGPRs)
typedef __attribute__((ext_vector_type(4))) float    floatx4; // MFMA C/D frag

// ---------------------------------------------------------------------------
// Prep: pack embeddings as f16 in MFMA-B frag-major layout
//   chunk c = (g*2 + ks)*64 + lane, lane = q*16 + n:
//   ehp[c] = e_f16[col = g*16+n][k = ks*32 + q*8 .. +8)
// One 32-col tile = 4 chunks = 4 KB contiguous. Also fp32 norms -> en[2048].
// ---------------------------------------------------------------------------
__global__ void prep_kernel(const float* __restrict__ emb,
                            half8* __restrict__ ehp, float* __restrict__ en) {
    const int t = blockIdx.x * 256 + threadIdx.x;   // 16384 threads
    {
        const int l   = t & 63;
        const int ks  = (t >> 6) & 1;
        const int g   = t >> 7;
        const int col = g * 16 + (l & 15);
        const int kb  = ks * 32 + (l >> 4) * 8;
        const float* s = emb + col * DIM + kb;
        float4 v0 = *(const float4*)s, v1 = *(const float4*)(s + 4);
        half8 hv;
        hv[0] = (_Float16)v0.x; hv[1] = (_Float16)v0.y;
        hv[2] = (_Float16)v0.z; hv[3] = (_Float16)v0.w;
        hv[4] = (_Float16)v1.x; hv[5] = (_Float16)v1.y;
        hv[6] = (_Float16)v1.z; hv[7] = (_Float16)v1.w;
        ehp[t] = hv;
    }
    if (t < NEMB * 4) {
        const int row = t >> 2, seg = t & 3;
        const float* s = emb + row * DIM + seg * 16;
        float acc = 0.f;
#pragma unroll
        for (int i = 0; i < 4; ++i) {
            float4 v = ((const float4*)s)[i];
            acc = fmaf(v.x, v.x, acc); acc = fmaf(v.y, v.y, acc);
            acc = fmaf(v.z, v.z, acc); acc = fmaf(v.w, v.w, acc);
        }
        acc += __shfl_xor(acc, 1, 64);
        acc += __shfl_xor(acc, 2, 64);
        if (seg == 0) en[row] = acc;
    }
}

// ---------------------------------------------------------------------------
// Main. Block = 4 waves, 64 rows. Wave pair p shares 32 rows; half h scans
// cols [h*1024, +1024) in 32 tiles of 32 cols. NO LDS staging: B-fragments
// are loaded straight to VGPRs (frag-major global layout -> one coalesced
// dwordx4 per chunk) with a 1-tile ping-pong register prefetch. Zero
// barriers / DMA hazards in the K-loop; LDS only holds norms + merge buf
// (10.3 KB) so occupancy is VGPR-bound at 4 waves/SIMD.
//   approx q = x.eh - ||e||^2/2 + 128 (f16 2-limb x, 1-limb e)
//   packed key = (bits(q) & ~63) | (63-L); branchless top-2 min/max/max.
//   Epilogue: exact fp32 rescore of 4 candidates (top-2 per half).
// ---------------------------------------------------------------------------
__global__ __launch_bounds__(256, 4) void vq_mfma_kernel(
        const float* __restrict__ x, const float* __restrict__ emb,
        const char* __restrict__ ehb, const float* __restrict__ eng,
        float* __restrict__ quant, float* __restrict__ idxf,
        float* __restrict__ flat) {

    __shared__ float EnS[NEMB];          // 8 KB: all norms
    __shared__ uint4 Mrg[2][64];         // 2 KB: per-half top-2 candidates

    const int t    = threadIdx.x;
    const int wave = t >> 6, lane = t & 63;
    const int n = lane & 15, q = lane >> 4;
    const int h = wave & 1, p = wave >> 1;
    const int blk0 = blockIdx.x * 64;
    const int row0 = blk0 + p * 32;

    // ---- flat_inputs copy (block-coalesced) ----
    {
        const float4* s4 = (const float4*)(x + (size_t)blk0 * DIM);
        float4*       d4 = (float4*)(flat + (size_t)blk0 * DIM);
#pragma unroll
        for (int i = 0; i < 4; ++i) d4[i * 256 + t] = s4[i * 256 + t];
    }
    // ---- stage all norms to LDS ----
    {
        const float4* s4 = (const float4*)eng;
        float4*       d4 = (float4*)EnS;
#pragma unroll
        for (int i = 0; i < 2; ++i) d4[i * 256 + t] = s4[i * 256 + t];
    }

    // ---- A fragments, f16 2-limb split. A[m=lane&15][k=q*8+j] ----
    half8 ah[2][2], al[2][2];
#pragma unroll
    for (int tl = 0; tl < 2; ++tl)
#pragma unroll
        for (int ks = 0; ks < 2; ++ks) {
            const float* pp = x + (size_t)(row0 + tl * 16 + n) * DIM + ks * 32 + q * 8;
            float4 v0 = *(const float4*)pp, v1 = *(const float4*)(pp + 4);
            float xv[8] = {v0.x, v0.y, v0.z, v0.w, v1.x, v1.y, v1.z, v1.w};
#pragma unroll
            for (int j = 0; j < 8; ++j) {
                _Float16 hh = (_Float16)xv[j];
                ah[tl][ks][j] = hh;
                al[tl][ks][j] = (_Float16)(xv[j] - (float)hh);
            }
        }

    __syncthreads();   // EnS visible to all waves

    unsigned best[8], sec[8];
#pragma unroll
    for (int r = 0; r < 8; ++r) { best[r] = 0u; sec[r] = 0u; }

    // per-lane stream base: chunk (h*128 + tile*4 + i), 1 KB/chunk, lane*16 within
    const char* ebase = ehb + (size_t)h * 131072 + (size_t)lane * 16;

    half8 bbuf[2][4];
    float enc[2][2];
    // ---- prologue: tile 0 fragments + norms into buffer 0 ----
#pragma unroll
    for (int i = 0; i < 4; ++i)
        bbuf[0][i] = *(const half8*)(ebase + i * 1024);
#pragma unroll
    for (int s = 0; s < 2; ++s)
        enc[0][s] = EnS[h * 1024 + s * 16 + n];

#pragma unroll 2
    for (int tile = 0; tile < 32; ++tile) {
        const int buf = tile & 1;
        if (tile < 31) {
            const char* src = ebase + (size_t)(tile + 1) * 4096;
#pragma unroll
            for (int i = 0; i < 4; ++i)
                bbuf[buf ^ 1][i] = *(const half8*)(src + i * 1024);
#pragma unroll
            for (int s = 0; s < 2; ++s)
                enc[buf ^ 1][s] = EnS[h * 1024 + (tile + 1) * 32 + s * 16 + n];
        }

#pragma unroll
        for (int sub = 0; sub < 2; ++sub) {
            const int L = tile * 2 + sub;
            const float enh = fmaf(-0.5f, enc[buf][sub], 128.0f);
            floatx4 a0 = {enh, enh, enh, enh};
            floatx4 a1 = a0;
            half8 bk0 = bbuf[buf][sub * 2 + 0];
            half8 bk1 = bbuf[buf][sub * 2 + 1];
            a0 = __builtin_amdgcn_mfma_f32_16x16x32_f16(ah[0][0], bk0, a0, 0, 0, 0);
            a1 = __builtin_amdgcn_mfma_f32_16x16x32_f16(ah[1][0], bk0, a1, 0, 0, 0);
            a0 = __builtin_amdgcn_mfma_f32_16x16x32_f16(al[0][0], bk0, a0, 0, 0, 0);
            a1 = __builtin_amdgcn_mfma_f32_16x16x32_f16(al[1][0], bk0, a1, 0, 0, 0);
            a0 = __builtin_amdgcn_mfma_f32_16x16x32_f16(ah[0][1], bk1, a0, 0, 0, 0);
            a1 = __builtin_amdgcn_mfma_f32_16x16x32_f16(ah[1][1], bk1, a1, 0, 0, 0);
            a0 = __builtin_amdgcn_mfma_f32_16x16x32_f16(al[0][1], bk1, a0, 0, 0, 0);
            a1 = __builtin_amdgcn_mfma_f32_16x16x32_f16(al[1][1], bk1, a1, 0, 0, 0);

            const unsigned Lp = (unsigned)(63 - L);
#pragma unroll
            for (int r = 0; r < 8; ++r) {
                float v = (r < 4) ? a0[r] : a1[r - 4];
                unsigned key = (__float_as_uint(v) & 0xFFFFFFC0u) | Lp;  // v_and_or_b32
                unsigned lo  = best[r] < key ? best[r] : key;
                best[r] = best[r] > key ? best[r] : key;
                sec[r]  = sec[r] > lo ? sec[r] : lo;
            }
        }
    }

    // ---- decode per-lane top-2 to (bucketed bits, full col) ----
    unsigned bval[8], bcol[8], sval[8], scol[8];
#pragma unroll
    for (int r = 0; r < 8; ++r) {
        bval[r] = best[r] & 0xFFFFFFC0u;
        bcol[r] = (unsigned)(h * 1024 + (63 - (int)(best[r] & 63u)) * 16 + n);
        sval[r] = sec[r] & 0xFFFFFFC0u;
        scol[r] = (unsigned)(h * 1024 + (63 - (int)(sec[r] & 63u)) * 16 + n);
    }
    // ---- butterfly top-2 merge across the 16 n-lanes of each q-group ----
#pragma unroll
    for (int m = 1; m < 16; m <<= 1) {
#pragma unroll
        for (int r = 0; r < 8; ++r) {
            unsigned ov  = (unsigned)__shfl_xor((int)bval[r], m, 64);
            unsigned oc  = (unsigned)__shfl_xor((int)bcol[r], m, 64);
            unsigned ov2 = (unsigned)__shfl_xor((int)sval[r], m, 64);
            unsigned oc2 = (unsigned)__shfl_xor((int)scol[r], m, 64);
            bool ow = (ov > bval[r]) || (ov == bval[r] && oc < bcol[r]);
            unsigned nbv = ow ? ov : bval[r], nbc = ow ? oc : bcol[r];
            unsigned lv  = ow ? bval[r] : ov, lc  = ow ? bcol[r] : oc;
            bool sv2 = (ov2 > sval[r]) || (ov2 == sval[r] && oc2 < scol[r]);
            unsigned bsv = sv2 ? ov2 : sval[r], bsc = sv2 ? oc2 : scol[r];
            bool s3 = (lv > bsv) || (lv == bsv && lc < bsc);
            sval[r] = s3 ? lv : bsv; scol[r] = s3 ? lc : bsc;
            bval[r] = nbv; bcol[r] = nbc;
        }
    }
    // ---- publish per-half candidates (rows: tl*16 + q*4 + r) ----
    if (n == 0) {
#pragma unroll
        for (int r = 0; r < 8; ++r) {
            const int lr = p * 32 + (r >> 2) * 16 + q * 4 + (r & 3);
            Mrg[h][lr] = make_uint4(bval[r], bcol[r], sval[r], scol[r]);
        }
    }
    __syncthreads();

    // ---- exact fp32 rescore of 4 candidates; wave w handles 16 rows ----
#pragma unroll
    for (int r = 0; r < 4; ++r) {
        const int lr   = wave * 16 + q * 4 + r;
        const int grow = blk0 + lr;
        uint4 c0v = Mrg[0][lr], c1v = Mrg[1][lr];
        int cand[4] = {(int)c0v.y, (int)c0v.w, (int)c1v.y, (int)c1v.w};
        float4 xv = *(const float4*)(x + (size_t)grow * DIM + n * 4);
        float pbest = -FLT_MAX; int cbest = 0;
        float4 ebest = {0.f, 0.f, 0.f, 0.f};
#pragma unroll
        for (int c = 0; c < 4; ++c) {
            float4 e = *(const float4*)(emb + (size_t)cand[c] * DIM + n * 4);
            float pp = (xv.x - 0.5f * e.x) * e.x + (xv.y - 0.5f * e.y) * e.y
                     + (xv.z - 0.5f * e.z) * e.z + (xv.w - 0.5f * e.w) * e.w;
#pragma unroll
            for (int m2 = 1; m2 < 16; m2 <<= 1) pp += __shfl_xor(pp, m2, 64);
            bool take = (pp > pbest) || (pp == pbest && cand[c] < cbest);
            pbest = take ? pp : pbest;
            cbest = take ? cand[c] : cbest;
            ebest.x = take ? e.x : ebest.x; ebest.y = take ? e.y : ebest.y;
            ebest.z = take ? e.z : ebest.z; ebest.w = take ? e.w : ebest.w;
        }
        *(float4*)(quant + (size_t)grow * DIM + n * 4) = ebest;
        if (n == 0) idxf[grow] = (float)cbest;
    }
}

extern "C" void kernel_launch(void* const* d_in, const int* in_sizes, int n_in,
                              void* d_out, int out_size, void* d_ws, size_t ws_size,
                              hipStream_t stream) {
    const float* x   = (const float*)d_in[0];   // [65536, 64]
    const float* emb = (const float*)d_in[1];   // [2048, 64]
    float* out   = (float*)d_out;
    float* quant = out;                               // 4194304 floats
    float* idxf  = out + (size_t)N_TOTAL * DIM;       // 65536 floats
    float* flat  = idxf + N_TOTAL;                    // 4194304 floats

    half8* ehp = (half8*)d_ws;                        // 2048*64 f16 frag-major (256 KB)
    float* en  = (float*)((char*)d_ws + (size_t)NEMB * DIM * 2);  // 2048 f32

    prep_kernel<<<64, 256, 0, stream>>>(emb, ehp, en);
    vq_mfma_kernel<<<N_TOTAL / 64, 256, 0, stream>>>(x, emb, (const char*)ehp, en,
                                                     quant, idxf, flat);
}